// Round 11
// baseline (558.233 us; speedup 1.0000x reference)
//
#include <hip/hip_runtime.h>
#include <hip/hip_bf16.h>

typedef __attribute__((ext_vector_type(8))) short bf16x8;
typedef __attribute__((ext_vector_type(4))) float f32x4;
typedef unsigned short u16;
typedef unsigned int u32;

__device__ __forceinline__ u32 bf16_rne(float f) {
  u32 u = __float_as_uint(f);
  return (u + 0x7FFFu + ((u >> 16) & 1u)) >> 16;
}
__device__ __forceinline__ float bf16_val(u32 b) { return __uint_as_float(b << 16); }

// ---- DPP rotation reduce within a 16-lane row: VALU pipe, not LDS ----
template <int CTRL>
__device__ __forceinline__ float dppmv(float x) {
  return __int_as_float(
      __builtin_amdgcn_mov_dpp(__float_as_int(x), CTRL, 0xF, 0xF, true));
}
__device__ __forceinline__ float rowsum16(float t) {
  t += dppmv<0x128>(t);   // row_ror:8
  t += dppmv<0x124>(t);   // row_ror:4
  t += dppmv<0x122>(t);   // row_ror:2
  t += dppmv<0x121>(t);   // row_ror:1
  return t;
}
__device__ __forceinline__ float rowmax16(float t) {
  t = fmaxf(t, dppmv<0x128>(t));
  t = fmaxf(t, dppmv<0x124>(t));
  t = fmaxf(t, dppmv<0x122>(t));
  t = fmaxf(t, dppmv<0x121>(t));
  return t;
}

// ---- split fp32 array into bf16 hi/lo (no transpose) ----
__global__ void split_arr(const float* __restrict__ in,
                          u16* __restrict__ hi, u16* __restrict__ lo, int n4) {
  int i = blockIdx.x * 256 + threadIdx.x;
  if (i >= n4) return;
  float4 v = ((const float4*)in)[i];
  u32 h0 = bf16_rne(v.x), h1 = bf16_rne(v.y), h2 = bf16_rne(v.z), h3 = bf16_rne(v.w);
  u32 l0 = bf16_rne(v.x - bf16_val(h0));
  u32 l1 = bf16_rne(v.y - bf16_val(h1));
  u32 l2 = bf16_rne(v.z - bf16_val(h2));
  u32 l3 = bf16_rne(v.w - bf16_val(h3));
  ushort4 hv; hv.x = (u16)h0; hv.y = (u16)h1; hv.z = (u16)h2; hv.w = (u16)h3;
  ushort4 lv; lv.x = (u16)l0; lv.y = (u16)l1; lv.z = (u16)l2; lv.w = (u16)l3;
  ((ushort4*)hi)[i] = hv;
  ((ushort4*)lo)[i] = lv;
}

// ---- transpose each 256x256 fp32 slice and split into bf16 hi/lo arrays ----
__global__ void split_transpose256(const float* __restrict__ in,
                                   u16* __restrict__ hi, u16* __restrict__ lo) {
  __shared__ float tile[32][33];
  const size_t off = (size_t)blockIdx.z * 65536;
  const int tx = threadIdx.x, ty = threadIdx.y;
#pragma unroll
  for (int i = 0; i < 4; ++i) {
    int y = blockIdx.y * 32 + ty + i * 8;
    int x = blockIdx.x * 32 + tx;
    tile[ty + i * 8][tx] = in[off + (size_t)y * 256 + x];
  }
  __syncthreads();
#pragma unroll
  for (int i = 0; i < 4; ++i) {
    float v = tile[tx][ty + i * 8];
    u32 hb = bf16_rne(v);
    u32 lb = bf16_rne(v - bf16_val(hb));
    size_t idx = off + (size_t)(blockIdx.x * 32 + ty + i * 8) * 256 + blockIdx.y * 32 + tx;
    hi[idx] = (u16)hb;
    lo[idx] = (u16)lb;
  }
}

// ---------------- fused priors-GEMM (split-bf16) + dynamic routing ----------------
// ROUND-11 = ROUND-8 ROUTING + BARRIER-FREE GEMM (A and W both global->VGPR).
// Round-10 post-mortem: 32x32 shape refuted (MFMA-busy flat, +8.4M conflicts);
// round-8 is the base. Rationale here: A, like W, is L2-resident (each A slab
// read by all 64 kk-blocks), so the LDS round-trip for A existed only for
// intra-block sharing. Loading A per-wave from global (coalesced: 64 lanes =
// 16x64B contiguous segments; 4x intra-block redundancy ~23 B/cyc/CU on L2)
// removes ALL staging DMA, ALL GEMM ds_reads and ALL GEMM barriers -- the 8
// waves/CU run fully async until the first routing barrier, covering each
// other's VMEM latency (they are no longer lockstepped).
// M=128/block, 256 thr = 4 waves eg(4), wave tile 128x64, acc[8][4]=128 regs,
// __launch_bounds__(256,2) (2 waves/SIMD is the RF cap: P-state=128KB/block;
// rounds 1/5/9 proved tighter bounds spill GBs).
// Prefetch: W one-slice-ahead (16 regs), A one-mt-ahead ping-pong (8 regs).
// Routing: scale-folded logits (unscaled s pre-barrier, scale post), iter-
// parity dbuf, all-wave redundant softmax, DPP rowsum16. 1 barrier/iter.
template <int R>
__global__ __launch_bounds__(256, 2) void caps_route(
    const u16* __restrict__ Ahi_g,   // [ab][128 rows][256] bf16-hi
    const u16* __restrict__ Alo_g,
    const u16* __restrict__ Whi,     // [KN][256][256] (transposed [e][d])
    const u16* __restrict__ Wlo,
    u16* __restrict__ o1hi, u16* __restrict__ o1lo,   // stage1 out (split)
    float* __restrict__ outp,                          // stage2 out
    int KN, int stage) {
  constexpr int SEG = 128 / R;              // routings per block (1 or 2)
  constexpr int MTS = 8 / SEG;              // m-tiles per routing
  constexpr int ABS = (R == 128) ? 6 : 5;   // log2(a-blocks in grid)
  __shared__ __align__(16) float wlog[2][4][128];   // iter-parity double buffer
  __shared__ __align__(16) float probs[128];
  __shared__ float sqpart[2][2][4];

  const int tid = threadIdx.x;
  const int w = tid >> 6, lane = tid & 63, q = lane >> 4, li = lane & 15;
  const int eg = w;                         // wave = column group
  const int kk = blockIdx.x >> ABS;         // weight slice (h or c)
  const int ab = blockIdx.x & ((1 << ABS) - 1);

  // ---- per-lane global fragment pointers ----
  // A frag (mt,ks): gA? + mt*4096 + ks*32 ; row = mt*16+li, k-granule q.
  // W frag (ct,ks): gW? + ct*4096 + ks*32 ; e = eg*64+ct*16+li, k-granule q.
  const u16* gA_h = Ahi_g + (size_t)ab * 32768 + (size_t)li * 256 + q * 8;
  const u16* gA_l = Alo_g + (size_t)ab * 32768 + (size_t)li * 256 + q * 8;
  const u16* gWh = Whi + (size_t)kk * 65536 + (size_t)(eg * 64 + li) * 256 + q * 8;
  const u16* gWl = Wlo + (size_t)kk * 65536 + (size_t)(eg * 64 + li) * 256 + q * 8;

  f32x4 acc[8][4] = {};

  // prologue: W(0) + A(mt=0, ks=0)
  bf16x8 bh[4], bl[4];
#pragma unroll
  for (int ct = 0; ct < 4; ++ct) {
    bh[ct] = *(const bf16x8*)(gWh + ct * 4096);
    bl[ct] = *(const bf16x8*)(gWl + ct * 4096);
  }
  bf16x8 ahc = *(const bf16x8*)(gA_h);
  bf16x8 alc = *(const bf16x8*)(gA_l);

  // ---- GEMM main loop: barrier-free, fully per-wave ----
#pragma unroll
  for (int ks = 0; ks < 8; ++ks) {
    bf16x8 nbh[4], nbl[4];
    if (ks < 7) {
#pragma unroll
      for (int ct = 0; ct < 4; ++ct) {                 // W(ks+1) prefetch
        nbh[ct] = *(const bf16x8*)(gWh + ct * 4096 + (ks + 1) * 32);
        nbl[ct] = *(const bf16x8*)(gWl + ct * 4096 + (ks + 1) * 32);
      }
    }
#pragma unroll
    for (int mt = 0; mt < 8; ++mt) {
      bf16x8 ahn, aln;
      if (!(mt == 7 && ks == 7)) {                     // A one-mt-ahead ping-pong
        const int nmt = (mt + 1) & 7;
        const int nks = (mt < 7) ? ks : ks + 1;
        ahn = *(const bf16x8*)(gA_h + nmt * 4096 + nks * 32);
        aln = *(const bf16x8*)(gA_l + nmt * 4096 + nks * 32);
      }
#pragma unroll
      for (int ct = 0; ct < 4; ++ct) {
        acc[mt][ct] = __builtin_amdgcn_mfma_f32_16x16x32_bf16(alc, bh[ct], acc[mt][ct], 0, 0, 0);
        acc[mt][ct] = __builtin_amdgcn_mfma_f32_16x16x32_bf16(ahc, bl[ct], acc[mt][ct], 0, 0, 0);
        acc[mt][ct] = __builtin_amdgcn_mfma_f32_16x16x32_bf16(ahc, bh[ct], acc[mt][ct], 0, 0, 0);
      }
      if (!(mt == 7 && ks == 7)) { ahc = ahn; alc = aln; }
    }
    if (ks < 7) {
#pragma unroll
      for (int ct = 0; ct < 4; ++ct) { bh[ct] = nbh[ct]; bl[ct] = nbl[ct]; }
    }
  }

  // ---- dynamic routing (3 iterations), 1 barrier per iter (round-8) ----
  const float invR = 1.0f / R;
  float v[SEG][4];
  float scl[SEG];
  float lg0 = 0.f, lg1 = 0.f;                          // running logits (all waves)

  for (int iter = 0; iter < 3; ++iter) {
    const int par = iter & 1;
    float4 p4[8];
    if (iter == 0) {
#pragma unroll
      for (int mt = 0; mt < 8; ++mt) {
        p4[mt].x = invR; p4[mt].y = invR; p4[mt].z = invR; p4[mt].w = invR;
      }
    } else {
#pragma unroll
      for (int mt = 0; mt < 8; ++mt)
        p4[mt] = *(const float4*)&probs[mt * 16 + q * 4];
    }
    // s[a][e] = sum_b probs[b] * P[b,e] : in-lane over (mt,rr), shfl over q
    float s[SEG][4];
#pragma unroll
    for (int sg = 0; sg < SEG; ++sg) {
#pragma unroll
      for (int ct = 0; ct < 4; ++ct) {
        float t = 0.f;
#pragma unroll
        for (int mi = 0; mi < MTS; ++mi) {
          const int mt = sg * MTS + mi;
          t += p4[mt].x * acc[mt][ct][0] + p4[mt].y * acc[mt][ct][1] +
               p4[mt].z * acc[mt][ct][2] + p4[mt].w * acc[mt][ct][3];
        }
        t += __shfl_xor(t, 16);
        t += __shfl_xor(t, 32);
        s[sg][ct] = t;
      }
    }
    // squash partials: sq_a = sum_e s_a[e]^2 (DPP over li; eg exchange via LDS)
#pragma unroll
    for (int sg = 0; sg < SEG; ++sg) {
      float ss = s[sg][0] * s[sg][0] + s[sg][1] * s[sg][1] +
                 s[sg][2] * s[sg][2] + s[sg][3] * s[sg][3];
      ss = rowsum16(ss);
      if (lane == 0) sqpart[par][sg][eg] = ss;
    }
    // logits partials with UNSCALED s (P.v = scale*(P.s); scale applied after)
    if (iter < 2) {
#pragma unroll
      for (int mt = 0; mt < 8; ++mt) {
        const int sg = mt / MTS;
        float tt[4];
#pragma unroll
        for (int rr = 0; rr < 4; ++rr) {
          float t = acc[mt][0][rr] * s[sg][0] + acc[mt][1][rr] * s[sg][1] +
                    acc[mt][2][rr] * s[sg][2] + acc[mt][3][rr] * s[sg][3];
          tt[rr] = rowsum16(t);
        }
        if (li == 0)
          *(float4*)&wlog[par][eg][mt * 16 + q * 4] =
              make_float4(tt[0], tt[1], tt[2], tt[3]);
      }
    }
    __syncthreads();                                   // the ONE barrier per iter
    // scale from squash
#pragma unroll
    for (int sg = 0; sg < SEG; ++sg) {
      float sq = sqpart[par][sg][0] + sqpart[par][sg][1] +
                 sqpart[par][sg][2] + sqpart[par][sg][3];
      scl[sg] = (sq > 0.f) ? sq / ((1.0f + sq) * sqrtf(sq)) : 0.f;
#pragma unroll
      for (int ct = 0; ct < 4; ++ct) v[sg][ct] = s[sg][ct] * scl[sg];
    }

    if (iter < 2) {
      // all-wave redundant softmax; logits += scale * sum_eg wlog
      int r0 = lane, r1 = lane + 64;
      float d0 = wlog[par][0][r0] + wlog[par][1][r0] + wlog[par][2][r0] + wlog[par][3][r0];
      float d1 = wlog[par][0][r1] + wlog[par][1][r1] + wlog[par][2][r1] + wlog[par][3][r1];
      if (R == 128) {
        lg0 += scl[0] * d0;
        lg1 += scl[0] * d1;
        float m = fmaxf(lg0, lg1);
        m = rowmax16(m);
        m = fmaxf(m, __shfl_xor(m, 16));
        m = fmaxf(m, __shfl_xor(m, 32));
        float e0 = __expf(lg0 - m), e1 = __expf(lg1 - m);
        float zz = e0 + e1;
        zz = rowsum16(zz);
        zz += __shfl_xor(zz, 16);
        zz += __shfl_xor(zz, 32);
        float inv = 1.0f / zz;
        probs[r0] = e0 * inv;
        probs[r1] = e1 * inv;
      } else {
        lg0 += scl[0] * d0;            // rows 0..63   = routing a0
        lg1 += scl[1] * d1;            // rows 64..127 = routing a1
        float m0 = rowmax16(lg0), m1 = rowmax16(lg1);
        m0 = fmaxf(m0, __shfl_xor(m0, 16));
        m0 = fmaxf(m0, __shfl_xor(m0, 32));
        m1 = fmaxf(m1, __shfl_xor(m1, 16));
        m1 = fmaxf(m1, __shfl_xor(m1, 32));
        float e0 = __expf(lg0 - m0), e1 = __expf(lg1 - m1);
        float z0 = rowsum16(e0), z1 = rowsum16(e1);
        z0 += __shfl_xor(z0, 16);
        z0 += __shfl_xor(z0, 32);
        z1 += __shfl_xor(z1, 16);
        z1 += __shfl_xor(z1, 32);
        probs[r0] = e0 / z0;
        probs[r1] = e1 / z1;
      }
      asm volatile("s_waitcnt lgkmcnt(0)" ::: "memory");  // own writes land before next-iter reads
    }
  }

  // ---- epilogue. stage1 -> split out1[a][kk][e]; stage2 -> fp32 out[kk][a][e] ----
  if (q == 0) {
#pragma unroll
    for (int sg = 0; sg < SEG; ++sg) {
      const int ag = ab * SEG + sg;      // global a
      if (stage == 1) {
        size_t ob = ((size_t)ag * KN + kk) * 256;
#pragma unroll
        for (int ct = 0; ct < 4; ++ct) {
          int e = eg * 64 + ct * 16 + li;
          u32 hb = bf16_rne(v[sg][ct]);
          u32 lb = bf16_rne(v[sg][ct] - bf16_val(hb));
          o1hi[ob + e] = (u16)hb;
          o1lo[ob + e] = (u16)lb;
        }
      } else {
        size_t ob = ((size_t)kk * 64 + ag) * 256;
#pragma unroll
        for (int ct = 0; ct < 4; ++ct) {
          int e = eg * 64 + ct * 16 + li;
          outp[ob + e] = v[sg][ct];
        }
      }
    }
  }
}

extern "C" void kernel_launch(void* const* d_in, const int* in_sizes, int n_in,
                              void* d_out, int out_size, void* d_ws, size_t ws_size,
                              hipStream_t stream) {
  const float* x  = (const float*)d_in[0];   // [64][128][256]
  const float* w1 = (const float*)d_in[1];   // [64][256][256]
  const float* wc = (const float*)d_in[2];   // [32][256][256]
  float* out = (float*)d_out;                // [32][64][256]

  char* ws = (char*)d_ws;
  u16* w1hi = (u16*)(ws);                    // 8 MB
  u16* w1lo = (u16*)(ws + (8u << 20));       // 8 MB
  u16* wchi = (u16*)(ws + (16u << 20));      // 4 MB
  u16* wclo = (u16*)(ws + (20u << 20));      // 4 MB
  u16* xhi  = (u16*)(ws + (24u << 20));      // 4 MB
  u16* xlo  = (u16*)(ws + (28u << 20));      // 4 MB
  u16* o1hi = (u16*)(ws + (32u << 20));      // 2 MB
  u16* o1lo = (u16*)(ws + (34u << 20));      // 2 MB

  split_arr<<<2048, 256, 0, stream>>>(x, xhi, xlo, 524288);
  split_transpose256<<<dim3(8, 8, 64), dim3(32, 8), 0, stream>>>(w1, w1hi, w1lo);
  split_transpose256<<<dim3(8, 8, 32), dim3(32, 8), 0, stream>>>(wc, wchi, wclo);
  // stage 1: 64 kk x 64 a-blocks (M=128 = 1 routing of R=128), 2 blocks/CU (reg-capped)
  caps_route<128><<<64 * 64, 256, 0, stream>>>(xhi, xlo, w1hi, w1lo, o1hi, o1lo, nullptr, 64, 1);
  // stage 2: 32 kk x 32 a-blocks (M=128 = 2 routings of R=64), 2 blocks/CU
  caps_route<64><<<32 * 32, 256, 0, stream>>>(o1hi, o1lo, wchi, wclo, nullptr, nullptr, out, 32, 2);
}